// Round 7
// baseline (650.459 us; speedup 1.0000x reference)
//
#include <hip/hip_runtime.h>
#include <hip/hip_bf16.h>

// B=2, L=4096, C=512, H=8, hd=64. f32 in/out; bf16 MFMA compute.
// v7: flash restructured for TLP+ILP: 16-query waves (8192 waves, 2048
// blocks, 10 KB LDS), hand software-pipelined K/V loads (A/B reg buffers,
// unroll 2), kh-pair merge with conflict-free stride-17 buffer. GEMM waves
// widened to 32 rows. XCD-pinned bh mapping kept (FETCH 70->12 MB in r6).

typedef __attribute__((ext_vector_type(8))) short short8;   // 8 bf16
typedef __attribute__((ext_vector_type(4))) float floatx4;  // MFMA C/D

#define MFMA(a, b, c) __builtin_amdgcn_mfma_f32_16x16x32_bf16((a), (b), (c), 0, 0, 0)

__device__ __forceinline__ unsigned short f2bf(float f) {
    unsigned int u = __builtin_bit_cast(unsigned int, f);
    return (unsigned short)((u + 0x7fffu + ((u >> 16) & 1u)) >> 16);  // RTNE
}
__device__ __forceinline__ unsigned int pack2(float lo, float hi) {
    __hip_bfloat162 h = __float22bfloat162_rn(make_float2(lo, hi));  // 1 instr
    unsigned int r;
    __builtin_memcpy(&r, &h, 4);
    return r;
}

__global__ __launch_bounds__(256) void conv_bf16(
    const float* __restrict__ src, ushort* __restrict__ dst, int n8)
{
    int i = blockIdx.x * blockDim.x + threadIdx.x;
    if (i >= n8) return;
    const float4* s = (const float4*)src + (size_t)i * 2;
    float4 a = s[0], b = s[1];
    uint4 r = { pack2(a.x, a.y), pack2(a.z, a.w), pack2(b.x, b.y), pack2(b.z, b.w) };
    *(uint4*)(dst + (size_t)i * 8) = r;
}

// RoPE LUT: lut[pos*32+j] = {cos, sin}(pos * 10000^(-j/32))
__global__ __launch_bounds__(256) void build_rope(float2* __restrict__ lut) {
    int i = blockIdx.x * 256 + threadIdx.x;   // 131072 entries
    int pos = i >> 5, j = i & 31;
    float invf = exp2f(-0.41524101186f * (float)j);
    float s, c;
    sincosf((float)pos * invf, &s, &c);
    lut[i] = make_float2(c, s);
}

// ---------------------------------------------------------------------------
// qkv = xb @ wb.T + b for G heads from h0; RoPE q,k (LUT); q pre-scaled 1/8;
// v transposed (hd, L). Wave tile 32(M) x 64(N), block M=128.
// ---------------------------------------------------------------------------
__global__ __launch_bounds__(256) void qkv_rope(
    const ushort* __restrict__ xb,    // (8192, 512) bf16
    const ushort* __restrict__ wb,    // (1536, 512) bf16
    const float* __restrict__ bias,   // (1536,) f32
    const float2* __restrict__ lut,   // (4096, 32)
    ushort* __restrict__ q, ushort* __restrict__ k, ushort* __restrict__ vt,
    int G, int h0)
{
    const int w_id = threadIdx.x >> 6;
    const int lane = threadIdx.x & 63;
    const int lr = lane & 15, quad = lane >> 4;
    const int m0 = blockIdx.x * 128 + w_id * 32;
    const int sec = blockIdx.y / G, hl = blockIdx.y % G;
    const int wc0 = sec * 512 + (h0 + hl) * 64;

    floatx4 acc[2][4] = {};
    const ushort* xrow0 = xb + (size_t)(m0 + lr) * 512 + quad * 8;
    const ushort* xrow1 = xb + (size_t)(m0 + 16 + lr) * 512 + quad * 8;
    for (int kk = 0; kk < 512; kk += 32) {
        short8 a0 = *(const short8*)(xrow0 + kk);
        short8 a1 = *(const short8*)(xrow1 + kk);
#pragma unroll
        for (int nt = 0; nt < 4; ++nt) {
            short8 b = *(const short8*)(wb + (size_t)(wc0 + nt * 16 + lr) * 512 + kk + quad * 8);
            acc[0][nt] = MFMA(a0, b, acc[0][nt]);
            acc[1][nt] = MFMA(a1, b, acc[1][nt]);
        }
    }

#pragma unroll
    for (int mt = 0; mt < 2; ++mt)
#pragma unroll
        for (int nt = 0; nt < 4; ++nt) {
            const int d = nt * 16 + lr;
            const float bv = bias[wc0 + d];
#pragma unroll
            for (int r = 0; r < 4; ++r) {
                const int row = m0 + mt * 16 + quad * 4 + r;
                const int b_ = row >> 12;
                const int pos = row & 4095;
                float val = acc[mt][nt][r] + bv;
                const size_t bhl = (size_t)(b_ * G + hl);
                if (sec < 2) {
                    float partner = __shfl_xor(val, 1);
                    float2 cs = lut[(pos << 5) | (d & 31)];
                    float rh = (d & 1) ? partner : -partner;   // rotate_half
                    float rv = val * cs.x + rh * cs.y;
                    if (sec == 0) rv *= 0.125f;                // softmax scale
                    ushort* dst = (sec == 0) ? q : k;
                    dst[(bhl * 4096 + pos) * 64 + d] = f2bf(rv);
                } else {
                    vt[(bhl * 64 + d) * 4096 + pos] = f2bf(val);
                }
            }
        }
}

// ---------------------------------------------------------------------------
// Flash v7. Block = 4 waves: w_id = qg + 2*kh. Wave = 16 queries
// (q0 = qtile*32 + qg*16) x 2048 keys (kh half), 32-key chunks, no-max
// softmax. K/V hand-pipelined (A/B reg buffers, unroll 2). P^T through
// per-wave parity-double-buffered LDS. kh pair merges (O,l) via LDS overlay.
// 1D grid: bhl = blockIdx.x % 2G (XCD-pinned for 2G=16).
// ---------------------------------------------------------------------------
__global__ __launch_bounds__(256) void flash_attn(
    const ushort* __restrict__ q, const ushort* __restrict__ k,
    const ushort* __restrict__ vt, ushort* __restrict__ o,
    int G, int h0)
{
    // P: [wave][parity][16 rows x 40 elems] (80 B stride: <=2-way banks).
    __shared__ __align__(16) ushort plds[4][2][16 * 40];   // 10240 B
    float* mb = (float*)plds;   // merge overlay (barrier-separated phase)
    const int w_id = threadIdx.x >> 6;
    const int lane = threadIdx.x & 63;
    const int lr = lane & 15, quad = lane >> 4;
    const int qg = w_id & 1, kh = w_id >> 1;
    const int nbh = 2 * G;
    const int bhl = blockIdx.x % nbh;
    const int qtile = blockIdx.x / nbh;
    const int b_ = bhl / G, hl = bhl % G;
    const int q0 = qtile * 32 + qg * 16;

    const ushort* qp = q + (size_t)bhl * 262144;
    const ushort* kp = k + (size_t)bhl * 262144;
    const ushort* vp = vt + (size_t)bhl * 262144;
    ushort* op = o + (size_t)b_ * 4096 * 512 + (size_t)(h0 + hl) * 64;

    // Q^T B-frags (q pre-scaled 1/8): B[k=d][n=query=lr]
    const ushort* qb = qp + (size_t)(q0 + lr) * 64 + quad * 8;
    short8 qf0 = *(const short8*)qb;
    short8 qf1 = *(const short8*)(qb + 32);

    floatx4 oacc[4] = {};      // O^T: d = 16dt + 4quad + r, query = lr
    float lsum = 0.f;
    const int kbase = kh * 2048;

    auto loadKV = [&](int kk, short8 (&ka)[2][2], short8 (&va)[4]) {
#pragma unroll
        for (int t = 0; t < 2; ++t) {
            const ushort* kb = kp + (size_t)(kk + 16 * t + lr) * 64 + quad * 8;
            ka[t][0] = *(const short8*)kb;
            ka[t][1] = *(const short8*)(kb + 32);
        }
#pragma unroll
        for (int dt = 0; dt < 4; ++dt)
            va[dt] = *(const short8*)(vp + (size_t)(16 * dt + lr) * 4096 + kk + quad * 8);
    };
    auto step = [&](int parity, short8 (&ka)[2][2], short8 (&va)[4]) {
        char* pw = (char*)&plds[w_id][parity][0];
        floatx4 st[2];
#pragma unroll
        for (int t = 0; t < 2; ++t) {
            floatx4 s = {};
            s = MFMA(ka[t][0], qf0, s);
            s = MFMA(ka[t][1], qf1, s);
            st[t] = s;
        }
#pragma unroll
        for (int t = 0; t < 2; ++t) {
            float p0 = __expf(st[t][0]), p1 = __expf(st[t][1]);
            float p2 = __expf(st[t][2]), p3 = __expf(st[t][3]);
            lsum += (p0 + p1) + (p2 + p3);
            uint2 u = { pack2(p0, p1), pack2(p2, p3) };
            *(uint2*)(pw + lr * 80 + t * 32 + quad * 8) = u;
        }
        short8 pf = *(const short8*)(pw + lr * 80 + quad * 16);
#pragma unroll
        for (int dt = 0; dt < 4; ++dt)
            oacc[dt] = MFMA(va[dt], pf, oacc[dt]);
    };

    short8 kaA[2][2], vaA[4], kaB[2][2], vaB[4];
    loadKV(kbase, kaA, vaA);
    for (int it = 0; it < 64; it += 2) {
        loadKV(kbase + (it + 1) * 32, kaB, vaB);   // prefetch odd
        step(0, kaA, vaA);
        if (it + 2 < 64) loadKV(kbase + (it + 2) * 32, kaA, vaA);  // prefetch even
        step(1, kaB, vaB);
    }

    // l across quads (queries in lr; quads hold disjoint keys)
    lsum += __shfl_xor(lsum, 16);
    lsum += __shfl_xor(lsum, 32);

    __syncthreads();   // all P reads done -> overlay merge buffer
    if (kh == 1) {
        float* m = mb + qg * 1104;
#pragma unroll
        for (int dt = 0; dt < 4; ++dt)
#pragma unroll
            for (int r = 0; r < 4; ++r)
                m[(16 * dt + 4 * quad + r) * 17 + lr] = oacc[dt][r];
        if (quad == 0) m[1088 + lr] = lsum;
    }
    __syncthreads();
    if (kh == 0) {
        float* m = mb + qg * 1104;
        float inv = 1.0f / (lsum + m[1088 + lr]);
#pragma unroll
        for (int dt = 0; dt < 4; ++dt)
#pragma unroll
            for (int c = 0; c < 2; ++c) {
                float v0 = (oacc[dt][2 * c]     + m[(16 * dt + 4 * quad + 2 * c) * 17 + lr]) * inv;
                float v1 = (oacc[dt][2 * c + 1] + m[(16 * dt + 4 * quad + 2 * c + 1) * 17 + lr]) * inv;
                *(unsigned int*)(op + (size_t)(q0 + lr) * 512 + 16 * dt + 4 * quad + 2 * c) =
                    pack2(v0, v1);
            }
    }
}

// ---------------------------------------------------------------------------
// out(f32) = o(bf16) @ wb.T + proj_b. Wave tile 32(M) x 64(N).
// ---------------------------------------------------------------------------
__global__ __launch_bounds__(256) void proj_gemm(
    const ushort* __restrict__ o,      // (8192, 512) bf16
    const ushort* __restrict__ wb,     // (512, 512) bf16
    const float* __restrict__ bias,    // (512,) f32
    float* __restrict__ out)           // (8192, 512) f32
{
    const int w_id = threadIdx.x >> 6;
    const int lane = threadIdx.x & 63;
    const int lr = lane & 15, quad = lane >> 4;
    const int m0 = blockIdx.x * 128 + w_id * 32;
    const int n0 = blockIdx.y * 64;

    floatx4 acc[2][4] = {};
    const ushort* orow0 = o + (size_t)(m0 + lr) * 512 + quad * 8;
    const ushort* orow1 = o + (size_t)(m0 + 16 + lr) * 512 + quad * 8;
    for (int kk = 0; kk < 512; kk += 32) {
        short8 a0 = *(const short8*)(orow0 + kk);
        short8 a1 = *(const short8*)(orow1 + kk);
#pragma unroll
        for (int nt = 0; nt < 4; ++nt) {
            short8 b = *(const short8*)(wb + (size_t)(n0 + nt * 16 + lr) * 512 + kk + quad * 8);
            acc[0][nt] = MFMA(a0, b, acc[0][nt]);
            acc[1][nt] = MFMA(a1, b, acc[1][nt]);
        }
    }
#pragma unroll
    for (int mt = 0; mt < 2; ++mt)
#pragma unroll
        for (int nt = 0; nt < 4; ++nt) {
            const int n = n0 + nt * 16 + lr;
            const float bv = bias[n];
#pragma unroll
            for (int r = 0; r < 4; ++r)
                out[(size_t)(m0 + mt * 16 + quad * 4 + r) * 512 + n] = acc[mt][nt][r] + bv;
        }
}

extern "C" void kernel_launch(void* const* d_in, const int* in_sizes, int n_in,
                              void* d_out, int out_size, void* d_ws, size_t ws_size,
                              hipStream_t stream)
{
    const float* x      = (const float*)d_in[0];
    const float* qkv_w  = (const float*)d_in[1];
    const float* qkv_b  = (const float*)d_in[2];
    const float* proj_w = (const float*)d_in[3];
    const float* proj_b = (const float*)d_in[4];
    float* out = (float*)d_out;

    const size_t MB = (size_t)1 << 20;
    ushort* base = (ushort*)d_ws;
    int G;
    ushort *xb, *o, *wb, *pwb, *q, *k, *vt;
    if (ws_size >= 34 * MB) {
        // G=8: single group -> o aliases xb (xb dead before flash runs)
        G = 8;
        xb = base; o = base;                 // 8 MiB shared
        wb  = base + 4194304;                // 1.5 MiB
        pwb = wb + 786432;                   // 0.5 MiB
        q   = pwb + 262144;
        k   = q + (size_t)G * 524288;
        vt  = k + (size_t)G * 524288;
    } else {
        G = (ws_size >= 30 * MB) ? 4 : (ws_size >= 24 * MB) ? 2 : 1;
        xb  = base;
        o   = base + 4194304;
        wb  = o + 4194304;
        pwb = wb + 786432;
        q   = pwb + 262144;
        k   = q + (size_t)G * 524288;
        vt  = k + (size_t)G * 524288;
    }

    // RoPE LUT in the head of d_out (1 MB) — dead before proj writes.
    float2* lut = (float2*)d_out;
    build_rope<<<512, 256, 0, stream>>>(lut);

    conv_bf16<<<2048, 256, 0, stream>>>(x, xb, 524288);
    conv_bf16<<<384, 256, 0, stream>>>(qkv_w, wb, 98304);
    conv_bf16<<<128, 256, 0, stream>>>(proj_w, pwb, 32768);

    for (int h0 = 0; h0 < 8; h0 += G) {
        qkv_rope<<<dim3(64, 3 * G), 256, 0, stream>>>(xb, wb, qkv_b, lut, q, k, vt, G, h0);
        flash_attn<<<128 * 2 * G, 256, 0, stream>>>(q, k, vt, o, G, h0);
    }
    proj_gemm<<<dim3(64, 8), 256, 0, stream>>>(o, pwb, proj_b, out);
}

// Round 8
// 433.225 us; speedup vs baseline: 1.5014x; 1.5014x over previous
//
#include <hip/hip_runtime.h>
#include <hip/hip_bf16.h>

// B=2, L=4096, C=512, H=8, hd=64. f32 in/out; bf16 MFMA compute.
// v8: deferred-PV software pipeline in flash: per 32-key chunk c --
//   rdP(P_{c-1}) ; ldK(c+1) ; QK(c) ; exp+wrP(c) ; PV(c-1) ; ldV(c+1)
// All latencies (VMEM ~200cy, LDS ~120cy) get >= 1 iteration of slack;
// the v5-v7 killer (same-iteration ds_write->ds_read RAW) is gone.
// 32 queries/wave, kh-split pairs, XCD-pinned bh (FETCH 70->12 MB, r6).

typedef __attribute__((ext_vector_type(8))) short short8;   // 8 bf16
typedef __attribute__((ext_vector_type(4))) float floatx4;  // MFMA C/D

#define MFMA(a, b, c) __builtin_amdgcn_mfma_f32_16x16x32_bf16((a), (b), (c), 0, 0, 0)

__device__ __forceinline__ unsigned short f2bf(float f) {
    unsigned int u = __builtin_bit_cast(unsigned int, f);
    return (unsigned short)((u + 0x7fffu + ((u >> 16) & 1u)) >> 16);  // RTNE
}
__device__ __forceinline__ unsigned int pack2(float lo, float hi) {
    __hip_bfloat162 h = __float22bfloat162_rn(make_float2(lo, hi));  // 1 instr
    unsigned int r;
    __builtin_memcpy(&r, &h, 4);
    return r;
}

__global__ __launch_bounds__(256) void conv_bf16(
    const float* __restrict__ src, ushort* __restrict__ dst, int n8)
{
    int i = blockIdx.x * blockDim.x + threadIdx.x;
    if (i >= n8) return;
    const float4* s = (const float4*)src + (size_t)i * 2;
    float4 a = s[0], b = s[1];
    uint4 r = { pack2(a.x, a.y), pack2(a.z, a.w), pack2(b.x, b.y), pack2(b.z, b.w) };
    *(uint4*)(dst + (size_t)i * 8) = r;
}

// RoPE LUT: lut[pos*32+j] = {cos, sin}(pos * 10000^(-j/32))
__global__ __launch_bounds__(256) void build_rope(float2* __restrict__ lut) {
    int i = blockIdx.x * 256 + threadIdx.x;   // 131072 entries
    int pos = i >> 5, j = i & 31;
    float invf = exp2f(-0.41524101186f * (float)j);
    float s, c;
    sincosf((float)pos * invf, &s, &c);
    lut[i] = make_float2(c, s);
}

// ---------------------------------------------------------------------------
// qkv = xb @ wb.T + b for G heads from h0; RoPE q,k (LUT); q pre-scaled 1/8;
// v transposed (hd, L). Wave tile 32(M) x 64(N), block M=128.
// ---------------------------------------------------------------------------
__global__ __launch_bounds__(256) void qkv_rope(
    const ushort* __restrict__ xb,    // (8192, 512) bf16
    const ushort* __restrict__ wb,    // (1536, 512) bf16
    const float* __restrict__ bias,   // (1536,) f32
    const float2* __restrict__ lut,   // (4096, 32)
    ushort* __restrict__ q, ushort* __restrict__ k, ushort* __restrict__ vt,
    int G, int h0)
{
    const int w_id = threadIdx.x >> 6;
    const int lane = threadIdx.x & 63;
    const int lr = lane & 15, quad = lane >> 4;
    const int m0 = blockIdx.x * 128 + w_id * 32;
    const int sec = blockIdx.y / G, hl = blockIdx.y % G;
    const int wc0 = sec * 512 + (h0 + hl) * 64;

    floatx4 acc[2][4] = {};
    const ushort* xrow0 = xb + (size_t)(m0 + lr) * 512 + quad * 8;
    const ushort* xrow1 = xb + (size_t)(m0 + 16 + lr) * 512 + quad * 8;
    for (int kk = 0; kk < 512; kk += 32) {
        short8 a0 = *(const short8*)(xrow0 + kk);
        short8 a1 = *(const short8*)(xrow1 + kk);
#pragma unroll
        for (int nt = 0; nt < 4; ++nt) {
            short8 b = *(const short8*)(wb + (size_t)(wc0 + nt * 16 + lr) * 512 + kk + quad * 8);
            acc[0][nt] = MFMA(a0, b, acc[0][nt]);
            acc[1][nt] = MFMA(a1, b, acc[1][nt]);
        }
    }

#pragma unroll
    for (int mt = 0; mt < 2; ++mt)
#pragma unroll
        for (int nt = 0; nt < 4; ++nt) {
            const int d = nt * 16 + lr;
            const float bv = bias[wc0 + d];
#pragma unroll
            for (int r = 0; r < 4; ++r) {
                const int row = m0 + mt * 16 + quad * 4 + r;
                const int b_ = row >> 12;
                const int pos = row & 4095;
                float val = acc[mt][nt][r] + bv;
                const size_t bhl = (size_t)(b_ * G + hl);
                if (sec < 2) {
                    float partner = __shfl_xor(val, 1);
                    float2 cs = lut[(pos << 5) | (d & 31)];
                    float rh = (d & 1) ? partner : -partner;   // rotate_half
                    float rv = val * cs.x + rh * cs.y;
                    if (sec == 0) rv *= 0.125f;                // softmax scale
                    ushort* dst = (sec == 0) ? q : k;
                    dst[(bhl * 4096 + pos) * 64 + d] = f2bf(rv);
                } else {
                    vt[(bhl * 64 + d) * 4096 + pos] = f2bf(val);
                }
            }
        }
}

// ---------------------------------------------------------------------------
// Flash v8. Block = 4 waves: w_id = qg + 2*kh. Wave = 32 queries (2 n-tiles,
// q0 = qtile*64 + qg*32) x 2048 keys (kh half) in 32-key chunks, no-max
// softmax. Deferred-PV pipeline (see header). kh pair merges (O,l) via LDS.
// 1D grid: bhl = blockIdx.x % 2G (XCD-pinned for 2G=16).
// ---------------------------------------------------------------------------
__global__ __launch_bounds__(256, 3) void flash_attn(
    const ushort* __restrict__ q, const ushort* __restrict__ k,
    const ushort* __restrict__ vt, ushort* __restrict__ o,
    int G, int h0)
{
    // P: [wave][parity][32 rows x 40 elems] (80 B stride: <=2-way banks).
    __shared__ __align__(16) ushort plds[4][2][32 * 40];   // 20480 B
    float* mb = (float*)plds;   // merge overlay (barrier-separated phase)
    const int w_id = threadIdx.x >> 6;
    const int lane = threadIdx.x & 63;
    const int lr = lane & 15, quad = lane >> 4;
    const int qg = w_id & 1, kh = w_id >> 1;
    const int nbh = 2 * G;
    const int bhl = blockIdx.x % nbh;
    const int qtile = blockIdx.x / nbh;
    const int b_ = bhl / G, hl = bhl % G;
    const int q0 = qtile * 64 + qg * 32;

    const ushort* qp = q + (size_t)bhl * 262144;
    const ushort* kp = k + (size_t)bhl * 262144;
    const ushort* vp = vt + (size_t)bhl * 262144;
    ushort* op = o + (size_t)b_ * 4096 * 512 + (size_t)(h0 + hl) * 64;
    char* pb0 = (char*)&plds[w_id][0][0];
    char* pb1 = (char*)&plds[w_id][1][0];

    // Q^T B-frags (q pre-scaled 1/8): qf[nn][c] = B[k=32c..][n=query 16nn+lr]
    short8 qf[2][2];
#pragma unroll
    for (int nn = 0; nn < 2; ++nn) {
        const ushort* qb = qp + (size_t)(q0 + 16 * nn + lr) * 64 + quad * 8;
        qf[nn][0] = *(const short8*)qb;
        qf[nn][1] = *(const short8*)(qb + 32);
    }

    floatx4 oacc[4][2] = {};   // [d-tile][n-tile]
    float lsum[2] = {0.f, 0.f};
    short8 ka0[2][2], ka1[2][2], va0[4], va1[4], pf[2];
    const int kbase = kh * 2048;

    auto ldK = [&](int kk, short8 (&ka)[2][2]) {
#pragma unroll
        for (int t = 0; t < 2; ++t) {
            const ushort* kb = kp + (size_t)(kk + 16 * t + lr) * 64 + quad * 8;
            ka[t][0] = *(const short8*)kb;
            ka[t][1] = *(const short8*)(kb + 32);
        }
    };
    auto ldV = [&](int kk, short8 (&va)[4]) {
#pragma unroll
        for (int dt = 0; dt < 4; ++dt)
            va[dt] = *(const short8*)(vp + (size_t)(16 * dt + lr) * 4096 + kk + quad * 8);
    };
    auto qk = [&](short8 (&ka)[2][2], floatx4 (&st)[2][2]) {
#pragma unroll
        for (int t = 0; t < 2; ++t)
#pragma unroll
            for (int nn = 0; nn < 2; ++nn) {
                floatx4 s = {};
                s = MFMA(ka[t][0], qf[nn][0], s);
                s = MFMA(ka[t][1], qf[nn][1], s);
                st[t][nn] = s;
            }
    };
    auto expw = [&](floatx4 (&st)[2][2], char* pw) {
#pragma unroll
        for (int t = 0; t < 2; ++t)
#pragma unroll
            for (int nn = 0; nn < 2; ++nn) {
                float p0 = __expf(st[t][nn][0]), p1 = __expf(st[t][nn][1]);
                float p2 = __expf(st[t][nn][2]), p3 = __expf(st[t][nn][3]);
                lsum[nn] += (p0 + p1) + (p2 + p3);
                uint2 u = { pack2(p0, p1), pack2(p2, p3) };
                *(uint2*)(pw + (16 * nn + lr) * 80 + t * 32 + quad * 8) = u;
            }
    };
    auto rdP = [&](char* pw) {
        pf[0] = *(const short8*)(pw + lr * 80 + quad * 16);
        pf[1] = *(const short8*)(pw + (16 + lr) * 80 + quad * 16);
    };
    auto pv = [&](short8 (&va)[4]) {
#pragma unroll
        for (int nn = 0; nn < 2; ++nn)
#pragma unroll
            for (int dt = 0; dt < 4; ++dt)
                oacc[dt][nn] = MFMA(va[dt], pf[nn], oacc[dt][nn]);
    };

    // prologue: chunk 0 (no PV yet), prefetch chunk 1
    ldK(kbase, ka0); ldV(kbase, va0);
    {
        floatx4 st[2][2];
        qk(ka0, st);
        ldK(kbase + 32, ka1);
        expw(st, pb0);
        ldV(kbase + 32, va1);
    }
    // steady state: chunks 1..62 in parity pairs
    for (int it = 1; it < 62; it += 2) {
        {   // chunk it (odd): P_{it-1} in pb0; write pb1; prefetch it+1 (even)
            rdP(pb0);
            ldK(kbase + (it + 1) * 32, ka0);
            floatx4 st[2][2];
            qk(ka1, st);
            expw(st, pb1);
            pv(va0);                           // PV_{it-1}
            ldV(kbase + (it + 1) * 32, va0);
        }
        {   // chunk it+1 (even): P_it in pb1; write pb0; prefetch it+2 (odd)
            rdP(pb1);
            ldK(kbase + (it + 2) * 32, ka1);
            floatx4 st[2][2];
            qk(ka0, st);
            expw(st, pb0);
            pv(va1);                           // PV_it
            ldV(kbase + (it + 2) * 32, va1);
        }
    }
    // epilogue: chunk 63 (odd, ka1/va1) + final PV
    rdP(pb0);                                  // P_62
    {
        floatx4 st[2][2];
        qk(ka1, st);
        expw(st, pb1);
    }
    pv(va0);                                   // PV_62
    rdP(pb1);                                  // P_63
    pv(va1);                                   // PV_63

    // l across quads (queries in lr; quads hold disjoint keys)
    lsum[0] += __shfl_xor(lsum[0], 16); lsum[0] += __shfl_xor(lsum[0], 32);
    lsum[1] += __shfl_xor(lsum[1], 16); lsum[1] += __shfl_xor(lsum[1], 32);

    __syncthreads();   // all P reads done -> overlay merge buffer
    if (kh == 1) {
        float* m = mb + qg * 2176;
#pragma unroll
        for (int dt = 0; dt < 4; ++dt)
#pragma unroll
            for (int nn = 0; nn < 2; ++nn)
#pragma unroll
                for (int r = 0; r < 4; ++r)
                    m[(16 * dt + 4 * quad + r) * 33 + 16 * nn + lr] = oacc[dt][nn][r];
        if (quad == 0) {
            m[2112 + lr] = lsum[0];
            m[2112 + 16 + lr] = lsum[1];
        }
    }
    __syncthreads();
    if (kh == 0) {
        float* m = mb + qg * 2176;
        float inv0 = 1.0f / (lsum[0] + m[2112 + lr]);
        float inv1 = 1.0f / (lsum[1] + m[2112 + 16 + lr]);
#pragma unroll
        for (int dt = 0; dt < 4; ++dt)
#pragma unroll
            for (int nn = 0; nn < 2; ++nn) {
                float inv = nn ? inv1 : inv0;
                float v0 = (oacc[dt][nn][0] + m[(16 * dt + 4 * quad + 0) * 33 + 16 * nn + lr]) * inv;
                float v1 = (oacc[dt][nn][1] + m[(16 * dt + 4 * quad + 1) * 33 + 16 * nn + lr]) * inv;
                float v2 = (oacc[dt][nn][2] + m[(16 * dt + 4 * quad + 2) * 33 + 16 * nn + lr]) * inv;
                float v3 = (oacc[dt][nn][3] + m[(16 * dt + 4 * quad + 3) * 33 + 16 * nn + lr]) * inv;
                uint2 u = { pack2(v0, v1), pack2(v2, v3) };
                *(uint2*)(op + (size_t)(q0 + 16 * nn + lr) * 512 + 16 * dt + 4 * quad) = u;
            }
    }
}

// ---------------------------------------------------------------------------
// out(f32) = o(bf16) @ wb.T + proj_b. Wave tile 32(M) x 64(N).
// ---------------------------------------------------------------------------
__global__ __launch_bounds__(256) void proj_gemm(
    const ushort* __restrict__ o,      // (8192, 512) bf16
    const ushort* __restrict__ wb,     // (512, 512) bf16
    const float* __restrict__ bias,    // (512,) f32
    float* __restrict__ out)           // (8192, 512) f32
{
    const int w_id = threadIdx.x >> 6;
    const int lane = threadIdx.x & 63;
    const int lr = lane & 15, quad = lane >> 4;
    const int m0 = blockIdx.x * 128 + w_id * 32;
    const int n0 = blockIdx.y * 64;

    floatx4 acc[2][4] = {};
    const ushort* orow0 = o + (size_t)(m0 + lr) * 512 + quad * 8;
    const ushort* orow1 = o + (size_t)(m0 + 16 + lr) * 512 + quad * 8;
    for (int kk = 0; kk < 512; kk += 32) {
        short8 a0 = *(const short8*)(orow0 + kk);
        short8 a1 = *(const short8*)(orow1 + kk);
#pragma unroll
        for (int nt = 0; nt < 4; ++nt) {
            short8 b = *(const short8*)(wb + (size_t)(n0 + nt * 16 + lr) * 512 + kk + quad * 8);
            acc[0][nt] = MFMA(a0, b, acc[0][nt]);
            acc[1][nt] = MFMA(a1, b, acc[1][nt]);
        }
    }
#pragma unroll
    for (int mt = 0; mt < 2; ++mt)
#pragma unroll
        for (int nt = 0; nt < 4; ++nt) {
            const int n = n0 + nt * 16 + lr;
            const float bv = bias[n];
#pragma unroll
            for (int r = 0; r < 4; ++r)
                out[(size_t)(m0 + mt * 16 + quad * 4 + r) * 512 + n] = acc[mt][nt][r] + bv;
        }
}

extern "C" void kernel_launch(void* const* d_in, const int* in_sizes, int n_in,
                              void* d_out, int out_size, void* d_ws, size_t ws_size,
                              hipStream_t stream)
{
    const float* x      = (const float*)d_in[0];
    const float* qkv_w  = (const float*)d_in[1];
    const float* qkv_b  = (const float*)d_in[2];
    const float* proj_w = (const float*)d_in[3];
    const float* proj_b = (const float*)d_in[4];
    float* out = (float*)d_out;

    const size_t MB = (size_t)1 << 20;
    ushort* base = (ushort*)d_ws;
    int G;
    ushort *xb, *o, *wb, *pwb, *q, *k, *vt;
    if (ws_size >= 34 * MB) {
        // G=8: single group -> o aliases xb (xb dead before flash runs)
        G = 8;
        xb = base; o = base;                 // 8 MiB shared
        wb  = base + 4194304;                // 1.5 MiB
        pwb = wb + 786432;                   // 0.5 MiB
        q   = pwb + 262144;
        k   = q + (size_t)G * 524288;
        vt  = k + (size_t)G * 524288;
    } else {
        G = (ws_size >= 30 * MB) ? 4 : (ws_size >= 24 * MB) ? 2 : 1;
        xb  = base;
        o   = base + 4194304;
        wb  = o + 4194304;
        pwb = wb + 786432;
        q   = pwb + 262144;
        k   = q + (size_t)G * 524288;
        vt  = k + (size_t)G * 524288;
    }

    // RoPE LUT in the head of d_out (1 MB) — dead before proj writes.
    float2* lut = (float2*)d_out;
    build_rope<<<512, 256, 0, stream>>>(lut);

    conv_bf16<<<2048, 256, 0, stream>>>(x, xb, 524288);
    conv_bf16<<<384, 256, 0, stream>>>(qkv_w, wb, 98304);
    conv_bf16<<<128, 256, 0, stream>>>(proj_w, pwb, 32768);

    for (int h0 = 0; h0 < 8; h0 += G) {
        qkv_rope<<<dim3(64, 3 * G), 256, 0, stream>>>(xb, wb, qkv_b, lut, q, k, vt, G, h0);
        flash_attn<<<64 * 2 * G, 256, 0, stream>>>(q, k, vt, o, G, h0);
    }
    proj_gemm<<<dim3(64, 8), 256, 0, stream>>>(o, pwb, proj_b, out);
}